// Round 1
// baseline (68.477 us; speedup 1.0000x reference)
//
#include <hip/hip_runtime.h>

#define BATCH 2048
#define EMB 16
#define NCOL 6  // 2 numeric + 4 categorical

// v row offsets for the 4 categorical features: 2 (numeric rows) + cumsum(CAT_SIZES)
#define ROFF0 2
#define ROFF1 (2 + 100000)
#define ROFF2 (2 + 150000)
#define ROFF3 (2 + 150020)

__global__ __launch_bounds__(256) void FM_44538810859522_kernel(
    const int* __restrict__ x,
    const float* __restrict__ v,
    const float* __restrict__ bias_user,
    const float* __restrict__ bias_item,
    const float* __restrict__ bias_genre,
    const float* __restrict__ bias_year,
    float* __restrict__ out)
{
    const int tid = blockIdx.x * blockDim.x + threadIdx.x;
    const int row = tid >> 4;   // 16 lanes per sample (one per emb dim)
    const int e   = tid & 15;
    if (row >= BATCH) return;

    const int* xr = x + row * NCOL;
    const float f0 = (float)xr[0];
    const float f1 = (float)xr[1];
    const int i0 = xr[2], i1 = xr[3], i2 = xr[4], i3 = xr[5];

    // Gather the 6 active rows of v (coalesced 64B per 16-lane group)
    const float a  = v[0 * EMB + e];
    const float b  = v[1 * EMB + e];
    const float c0 = v[(size_t)(ROFF0 + i0) * EMB + e];
    const float c1 = v[(size_t)(ROFF1 + i1) * EMB + e];
    const float c2 = v[(size_t)(ROFF2 + i2) * EMB + e];
    const float c3 = v[(size_t)(ROFF3 + i3) * EMB + e];

    const float s  = f0 * a + f1 * b + c0 + c1 + c2 + c3;
    const float ss = f0 * f0 * a * a + f1 * f1 * b * b
                   + c0 * c0 + c1 * c1 + c2 * c2 + c3 * c3;
    float t = 0.5f * (s * s - ss);

    // Reduce over the 16 emb lanes
    t += __shfl_xor(t, 8, 16);
    t += __shfl_xor(t, 4, 16);
    t += __shfl_xor(t, 2, 16);
    t += __shfl_xor(t, 1, 16);

    if (e == 0) {
        const float bias = bias_user[i0] + bias_item[i1]
                         + bias_genre[i2] + bias_year[i3];
        const float y = bias + t;
        out[row] = 1.0f / (1.0f + expf(-y));
    }
}

extern "C" void kernel_launch(void* const* d_in, const int* in_sizes, int n_in,
                              void* d_out, int out_size, void* d_ws, size_t ws_size,
                              hipStream_t stream) {
    const int*   x  = (const int*)d_in[0];
    const float* v  = (const float*)d_in[1];
    const float* bu = (const float*)d_in[2];
    const float* bi = (const float*)d_in[3];
    const float* bg = (const float*)d_in[4];
    const float* by = (const float*)d_in[5];
    float* out = (float*)d_out;

    const int threads = BATCH * EMB;          // 32768
    const int block = 256;
    const int grid = (threads + block - 1) / block;  // 128
    FM_44538810859522_kernel<<<grid, block, 0, stream>>>(x, v, bu, bi, bg, by, out);
}

// Round 2
// 67.570 us; speedup vs baseline: 1.0134x; 1.0134x over previous
//
#include <hip/hip_runtime.h>

#define BATCH 2048
#define EMB 16
#define NCOL 6  // 2 numeric + 4 categorical

// v row offsets for the 4 categorical features: 2 (numeric rows) + cumsum(CAT_SIZES)
#define ROFF0 2
#define ROFF1 (2 + 100000)
#define ROFF2 (2 + 150000)
#define ROFF3 (2 + 150020)

__global__ __launch_bounds__(256) void FM_44538810859522_kernel(
    const int* __restrict__ x,
    const float* __restrict__ v,
    const float* __restrict__ bias_user,
    const float* __restrict__ bias_item,
    const float* __restrict__ bias_genre,
    const float* __restrict__ bias_year,
    float* __restrict__ out)
{
    const int tid = blockIdx.x * blockDim.x + threadIdx.x;
    const int row = tid >> 2;   // 4 lanes per sample, one float4 (4 dims) per lane
    const int q   = tid & 3;
    if (row >= BATCH) return;

    const int* xr = x + row * NCOL;
    const float f0 = (float)xr[0];
    const float f1 = (float)xr[1];
    const int i0 = xr[2], i1 = xr[3], i2 = xr[4], i3 = xr[5];

    // Each v row = 16 floats = 4 float4; lane q takes quarter q.
    const float4* vv = (const float4*)v;
    const float4 a  = vv[0 * 4 + q];
    const float4 b  = vv[1 * 4 + q];
    const float4 c0 = vv[(size_t)(ROFF0 + i0) * 4 + q];
    const float4 c1 = vv[(size_t)(ROFF1 + i1) * 4 + q];
    const float4 c2 = vv[(size_t)(ROFF2 + i2) * 4 + q];
    const float4 c3 = vv[(size_t)(ROFF3 + i3) * 4 + q];

    float t = 0.0f;
    {
        float s, ss;
        s  = f0 * a.x + f1 * b.x + c0.x + c1.x + c2.x + c3.x;
        ss = f0 * f0 * a.x * a.x + f1 * f1 * b.x * b.x
           + c0.x * c0.x + c1.x * c1.x + c2.x * c2.x + c3.x * c3.x;
        t += 0.5f * (s * s - ss);
        s  = f0 * a.y + f1 * b.y + c0.y + c1.y + c2.y + c3.y;
        ss = f0 * f0 * a.y * a.y + f1 * f1 * b.y * b.y
           + c0.y * c0.y + c1.y * c1.y + c2.y * c2.y + c3.y * c3.y;
        t += 0.5f * (s * s - ss);
        s  = f0 * a.z + f1 * b.z + c0.z + c1.z + c2.z + c3.z;
        ss = f0 * f0 * a.z * a.z + f1 * f1 * b.z * b.z
           + c0.z * c0.z + c1.z * c1.z + c2.z * c2.z + c3.z * c3.z;
        t += 0.5f * (s * s - ss);
        s  = f0 * a.w + f1 * b.w + c0.w + c1.w + c2.w + c3.w;
        ss = f0 * f0 * a.w * a.w + f1 * f1 * b.w * b.w
           + c0.w * c0.w + c1.w * c1.w + c2.w * c2.w + c3.w * c3.w;
        t += 0.5f * (s * s - ss);
    }

    // Reduce over the 4 lanes of this sample
    t += __shfl_xor(t, 2, 4);
    t += __shfl_xor(t, 1, 4);

    if (q == 0) {
        const float bias = bias_user[i0] + bias_item[i1]
                         + bias_genre[i2] + bias_year[i3];
        const float y = bias + t;
        out[row] = 1.0f / (1.0f + expf(-y));
    }
}

extern "C" void kernel_launch(void* const* d_in, const int* in_sizes, int n_in,
                              void* d_out, int out_size, void* d_ws, size_t ws_size,
                              hipStream_t stream) {
    const int*   x  = (const int*)d_in[0];
    const float* v  = (const float*)d_in[1];
    const float* bu = (const float*)d_in[2];
    const float* bi = (const float*)d_in[3];
    const float* bg = (const float*)d_in[4];
    const float* by = (const float*)d_in[5];
    float* out = (float*)d_out;

    const int threads = BATCH * 4;            // 8192
    const int block = 256;
    const int grid = (threads + block - 1) / block;  // 32
    FM_44538810859522_kernel<<<grid, block, 0, stream>>>(x, v, bu, bi, bg, by, out);
}